// Round 5
// baseline (214.815 us; speedup 1.0000x reference)
//
#include <hip/hip_runtime.h>
#include <hip/hip_bf16.h>

// Problem constants (B=4, S=2048, D=1024, fp32 in/out)
#define BB 4
#define SS 2048
#define DD 1024

using f32x4  = __attribute__((ext_vector_type(4))) float;
using i32x8  = __attribute__((ext_vector_type(8))) int;

struct f8_t { unsigned char b; };

// async global->LDS, 16B per lane. LDS dest = wave-uniform base + lane*16.
__device__ __forceinline__ void gld16(const void* g, void* l) {
    __builtin_amdgcn_global_load_lds(
        (const __attribute__((address_space(1))) void*)(g),
        (__attribute__((address_space(3))) void*)(l),
        16, 0, 0);
}

__device__ __forceinline__ void store1(float* p, float v) { *p = v; }
__device__ __forceinline__ void store1(f8_t* p, float v)  {
    p->b = (unsigned char)(__builtin_amdgcn_cvt_pk_fp8_f32(v, v, 0, false) & 0xff);
}

// ---------------------------------------------------------------------------
// All fp32->fp8 conversions in one launch.
// Blocks [0,4096): x (nx/8 groups). Blocks [4096,5632): Wq,Wk,Wv (512 each).
// ---------------------------------------------------------------------------
__global__ void cvt_all_kernel(const float* __restrict__ x, const float* __restrict__ Wq,
                               const float* __restrict__ Wk, const float* __restrict__ Wv,
                               unsigned char* __restrict__ x8, unsigned char* __restrict__ w8) {
    const int bid = blockIdx.x;
    const float* src;
    unsigned char* dst;
    long j;
    if (bid < 4096) {
        src = x; dst = x8;
        j = (long)bid * 256 + threadIdx.x;
    } else {
        int lb = bid - 4096;
        int s  = lb >> 9;                       // 0,1,2 -> Wq,Wk,Wv
        src = (s == 0) ? Wq : (s == 1) ? Wk : Wv;
        dst = w8 + ((size_t)s << 20);           // nw = 1<<20 bytes per weight
        j = (long)(lb & 511) * 256 + threadIdx.x;
    }
    float4 a = ((const float4*)src)[2 * j];
    float4 b = ((const float4*)src)[2 * j + 1];
    int lo = __builtin_amdgcn_cvt_pk_fp8_f32(a.x, a.y, 0, false);
    lo     = __builtin_amdgcn_cvt_pk_fp8_f32(a.z, a.w, lo, true);
    int hi = __builtin_amdgcn_cvt_pk_fp8_f32(b.x, b.y, 0, false);
    hi     = __builtin_amdgcn_cvt_pk_fp8_f32(b.z, b.w, hi, true);
    ((int2*)dst)[j] = make_int2(lo, hi);
}

// ---------------------------------------------------------------------------
// xsum[b][d] = sum_s x[b][s][d]  (fp32, exact — colsum path needs fp32 x).
// ---------------------------------------------------------------------------
__global__ void xsum_kernel(const float* __restrict__ x, float* __restrict__ xsum) {
    int bd = blockIdx.x;
    int b  = bd >> 2, dc = bd & 3;
    int d  = dc * 256 + threadIdx.x;
    int s0 = blockIdx.y * 128;
    const float* p = x + ((size_t)b * SS + s0) * DD + d;
    float acc = 0.f;
    for (int i = 0; i < 128; ++i) acc += p[(size_t)i * DD];
    atomicAdd(&xsum[b * DD + d], acc);
}

// colsumV[b][c] = sum_d xsum[b][d] * Wv[c][d]   (one wave per output)
__global__ void colsumv_kernel(const float* __restrict__ Wv, const float* __restrict__ xsum,
                               float* __restrict__ colsum) {
    int idx  = blockIdx.x * 4 + (threadIdx.x >> 6);   // 0..4095
    int b    = idx >> 10, c = idx & 1023;
    int lane = threadIdx.x & 63;
    const float* wr = Wv + (size_t)c * DD;
    const float* xs = xsum + b * DD;
    float acc = 0.f;
#pragma unroll 4
    for (int d = lane; d < DD; d += 64) acc += wr[d] * xs[d];
#pragma unroll
    for (int off = 32; off; off >>= 1) acc += __shfl_xor(acc, off);
    if (lane == 0) colsum[idx] = acc;
}

// ---------------------------------------------------------------------------
// fp8 (e4m3) NT GEMM via MX-scaled MFMA 16x16x128. BK=128, 128x128 tile.
// 32B-granular XOR-4 LDS swizzle: staging chunk i of row r lands so that each
// lane's 32 contiguous k-bytes are contiguous in LDS -> fragment is ONE
// aligned i32x8 deref (2x ds_read_b128, adjacent VGPRs, no repack movs).
// Epilogue modes:
//   0: plain fp8 store             (QK projection)
//   1: col-batch-split fp8 store   (V^T)
//   2: scores: t=exp(acc*qmask/32)-1; store fp8 512t; atomicAdd row sums of t
//   3: PV: out = (acc*2^-9 + colsumV[d]) / (2048 + rsum[q]), fp32
// ---------------------------------------------------------------------------
template <int MODE, typename CT>
__global__ __launch_bounds__(256, 3) void gemm_f8(
    const unsigned char* __restrict__ A, const unsigned char* __restrict__ B,
    CT* __restrict__ C, int M, int N, int K,
    long batchA, long batchB, long batchC,
    int ldc, int col_shift, long cstride,
    const float* __restrict__ qmask, float* __restrict__ rsum,
    const float* __restrict__ colsum) {
    constexpr int BM = 128, BN = 128, BK = 128;
    constexpr int SCALE_A = (MODE == 3) ? 118 : 127;   // 2^-9 un-scales T' = 512 t
    __shared__ __attribute__((aligned(32))) unsigned char As[BM * BK];
    __shared__ __attribute__((aligned(32))) unsigned char Bs[BN * BK];

    const int tid  = threadIdx.x;
    const int lane = tid & 63;
    const int wv   = tid >> 6;
    const int l16  = lane & 15;
    const int quad = lane >> 4;
    const int wm   = wv >> 1;
    const int wn   = wv & 1;

    const int m0 = blockIdx.y * BM;
    const int n0 = blockIdx.x * BN;
    const long z = blockIdx.z;
    const unsigned char* Ab = A + z * batchA;
    const unsigned char* Bb = B + z * batchB;

    const int sw = (quad ^ (l16 & 3)) << 5;   // swizzled 32B offset for fragments

    f32x4 acc[4][4] = {};

    for (int kt = 0; kt < K; kt += BK) {
#pragma unroll
        for (int j = 0; j < 4; ++j) {
            int slot = j * 256 + wv * 64 + lane;       // 0..1023 (16B units)
            int r = slot >> 3;
            int c = (slot & 7) ^ ((r & 3) << 1);       // 32B-granular XOR swizzle
            gld16(Ab + (size_t)(m0 + r) * K + (kt + c * 16),
                  As + (size_t)(j * 256 + wv * 64) * 16);
        }
#pragma unroll
        for (int j = 0; j < 4; ++j) {
            int slot = j * 256 + wv * 64 + lane;
            int r = slot >> 3;
            int c = (slot & 7) ^ ((r & 3) << 1);
            gld16(Bb + (size_t)(n0 + r) * K + (kt + c * 16),
                  Bs + (size_t)(j * 256 + wv * 64) * 16);
        }
        asm volatile("s_waitcnt vmcnt(0)" ::: "memory");
        __syncthreads();

        i32x8 af[4], bfr[4];
#pragma unroll
        for (int i = 0; i < 4; ++i)
            af[i] = *(const i32x8*)(As + (wm * 64 + i * 16 + l16) * 128 + sw);
#pragma unroll
        for (int i = 0; i < 4; ++i)
            bfr[i] = *(const i32x8*)(Bs + (wn * 64 + i * 16 + l16) * 128 + sw);

#pragma unroll
        for (int i = 0; i < 4; ++i)
#pragma unroll
            for (int j = 0; j < 4; ++j)
                acc[i][j] = __builtin_amdgcn_mfma_scale_f32_16x16x128_f8f6f4(
                    af[i], bfr[j], acc[i][j], 0, 0, 0, SCALE_A, 0, 127);
        __syncthreads();
    }

    // ---------------- epilogue (C/D layout: col=lane&15, row=quad*4+reg) ----
    CT* Cb = C + z * batchC;

    if constexpr (MODE == 0) {
#pragma unroll
        for (int mi = 0; mi < 4; ++mi)
#pragma unroll
            for (int ni = 0; ni < 4; ++ni) {
                int colg = n0 + wn * 64 + ni * 16 + l16;
#pragma unroll
                for (int r = 0; r < 4; ++r) {
                    int rowg = m0 + wm * 64 + mi * 16 + quad * 4 + r;
                    store1(Cb + (size_t)rowg * ldc + colg, acc[mi][ni][r]);
                }
            }
    } else if constexpr (MODE == 1) {
#pragma unroll
        for (int mi = 0; mi < 4; ++mi)
#pragma unroll
            for (int ni = 0; ni < 4; ++ni) {
                int colg = n0 + wn * 64 + ni * 16 + l16;
                int cb   = colg >> col_shift;
                int ccol = colg - (cb << col_shift);
#pragma unroll
                for (int r = 0; r < 4; ++r) {
                    int rowg = m0 + wm * 64 + mi * 16 + quad * 4 + r;
                    store1(Cb + (long)cb * cstride + (size_t)rowg * ldc + ccol, acc[mi][ni][r]);
                }
            }
    } else if constexpr (MODE == 2) {
        const float* qm = qmask + (z << 11);
        float* rs = rsum + (z << 11);
#pragma unroll
        for (int mi = 0; mi < 4; ++mi) {
#pragma unroll
            for (int r = 0; r < 4; ++r) {
                int rowg = m0 + wm * 64 + mi * 16 + quad * 4 + r;
                float fac = qm[rowg] * 0.03125f;     // q_mask / sqrt(1024)
                float part = 0.f;
#pragma unroll
                for (int ni = 0; ni < 4; ++ni) {
                    int colg = n0 + wn * 64 + ni * 16 + l16;
                    float t = __expf(acc[mi][ni][r] * fac) - 1.0f;
                    part += t;
                    store1(Cb + (size_t)rowg * ldc + colg, t * 512.0f);
                }
                // reduce over the 16 lanes sharing this row
                part += __shfl_xor(part, 1);
                part += __shfl_xor(part, 2);
                part += __shfl_xor(part, 4);
                part += __shfl_xor(part, 8);
                if (l16 == 0) atomicAdd(&rs[rowg], part);
            }
        }
    } else {  // MODE == 3
        const float* rs = rsum + (z << 11);
        const float* cs = colsum + (z << 10);
#pragma unroll
        for (int mi = 0; mi < 4; ++mi) {
#pragma unroll
            for (int r = 0; r < 4; ++r) {
                int rowg = m0 + wm * 64 + mi * 16 + quad * 4 + r;
                float inv = 1.0f / (2048.0f + rs[rowg]);
#pragma unroll
                for (int ni = 0; ni < 4; ++ni) {
                    int colg = n0 + wn * 64 + ni * 16 + l16;
                    store1(Cb + (size_t)rowg * ldc + colg, (acc[mi][ni][r] + cs[colg]) * inv);
                }
            }
        }
    }
}

// ---------------------------------------------------------------------------
extern "C" void kernel_launch(void* const* d_in, const int* in_sizes, int n_in,
                              void* d_out, int out_size, void* d_ws, size_t ws_size,
                              hipStream_t stream) {
    const float* x     = (const float*)d_in[0];
    const float* Wq    = (const float*)d_in[1];
    const float* Wk    = (const float*)d_in[2];
    const float* Wv    = (const float*)d_in[3];
    const float* qmask = (const float*)d_in[4];
    float* out = (float*)d_out;

    const long nx = (long)BB * SS * DD;   // 8,388,608
    const long nw = (long)DD * DD;        // 1,048,576

    unsigned char* ws  = (unsigned char*)d_ws;
    unsigned char* x8  = ws;                          // x fp8         8.4 MB
    unsigned char* w8  = x8 + nx;                     // Wq,Wk,Wv fp8  3 MB
    unsigned char* qk8 = w8 + 3 * nw;                 // Q,K fp8       16.8 MB
    unsigned char* vt8 = qk8 + 2 * nx;                // V^T fp8 (B,D,S) 8.4 MB
    unsigned char* t8  = vt8 + nx;                    // T = 512(exp-1) fp8 (B,S,S) 16.8 MB
    float* xsum   = (float*)(t8 + (long)BB * SS * SS);// (B,D) 16 KB
    float* rs     = xsum + BB * DD;                   // (B,S) 32 KB  (Σt per row)
    float* colsum = rs + BB * SS;                     // (B,D) 16 KB

    // 0. zero the accumulators (xsum and rs are adjacent)
    hipMemsetAsync(xsum, 0, (size_t)(BB * DD + BB * SS) * sizeof(float), stream);

    // 1. conversions (one launch) + exact colsum(V) path
    cvt_all_kernel<<<dim3(4096 + 1536), dim3(256), 0, stream>>>(x, Wq, Wk, Wv, x8, w8);
    xsum_kernel<<<dim3(16, 16), dim3(256), 0, stream>>>(x, xsum);
    colsumv_kernel<<<dim3(1024), dim3(256), 0, stream>>>(Wv, xsum, colsum);

    // 2. Q = x@Wq^T, K = x@Wk^T  (fp8 MX GEMM, z=2, fp8 out)
    gemm_f8<0, f8_t><<<dim3(DD / 128, (BB * SS) / 128, 2), 256, 0, stream>>>(
        x8, w8, (f8_t*)qk8, BB * SS, DD, DD, 0, nw, nx, DD, 31, 0, nullptr, nullptr, nullptr);

    // 3. V^T = Wv @ x^T -> (B, D, S) fp8, col-batch-split store
    gemm_f8<1, f8_t><<<dim3((BB * SS) / 128, DD / 128, 1), 256, 0, stream>>>(
        w8 + 2 * nw, x8, (f8_t*)vt8, DD, BB * SS, DD, 0, 0, 0, SS, 11, (long)DD * SS,
        nullptr, nullptr, nullptr);

    // 4. T = exp(mask*scores)-1 (x512, fp8) + row sums of t (atomics)
    gemm_f8<2, f8_t><<<dim3(SS / 128, SS / 128, BB), 256, 0, stream>>>(
        qk8, qk8 + nx, (f8_t*)t8, SS, SS, DD, (long)SS * DD, (long)SS * DD, (long)SS * SS,
        SS, 31, 0, qmask, rs, nullptr);

    // 5. out = (T@V * 2^-9 + colsumV) / (2048 + rowsum_t), fp32
    gemm_f8<3, float><<<dim3(DD / 128, SS / 128, BB), 256, 0, stream>>>(
        t8, vt8, out, SS, DD, SS, (long)SS * SS, (long)DD * SS, (long)SS * DD,
        DD, 31, 0, nullptr, rs, colsum);
}